// Round 3
// baseline (5001.751 us; speedup 1.0000x reference)
//
#include <hip/hip_runtime.h>
#include <cstddef>

// order-preserving float -> uint encoding for atomicMax over signed floats
__device__ __forceinline__ unsigned fenc(float f) {
    unsigned b = __float_as_uint(f);
    return (b & 0x80000000u) ? ~b : (b | 0x80000000u);
}
__device__ __forceinline__ float fdec(unsigned u) {
    return (u & 0x80000000u) ? __uint_as_float(u & 0x7fffffffu) : __uint_as_float(~u);
}

__device__ __forceinline__ float leaky02(float v) { return v > 0.f ? v : 0.2f * v; }

// ---------------- grid-stride zero fill --------------------------------------
__global__ void zero_f32(float* __restrict__ p, int n)
{
    for (int i = blockIdx.x * blockDim.x + threadIdx.x; i < n;
         i += gridDim.x * blockDim.x)
        p[i] = 0.f;
}

// ---------------- h = x @ W ; alpha_src = h.a_src ; alpha_dst = h.a_dst ------
// one block (128 threads) per node row
__global__ void gemm_alpha(const float* __restrict__ x,
                           const float* __restrict__ W,
                           const float* __restrict__ avs, const float* __restrict__ avd,
                           float* __restrict__ h, float* __restrict__ asrc,
                           float* __restrict__ adst)
{
    const int row = blockIdx.x;
    const int t   = threadIdx.x;
    __shared__ float xs[128];
    __shared__ float r1[128];
    __shared__ float r2[128];

    xs[t] = x[(size_t)row * 128 + t];
    __syncthreads();

    float acc = 0.f;
#pragma unroll 16
    for (int k = 0; k < 128; ++k)
        acc += xs[k] * W[k * 128 + t];

    h[(size_t)row * 128 + t] = acc;
    r1[t] = acc * avs[t];
    r2[t] = acc * avd[t];
    __syncthreads();
    for (int s = 64; s > 0; s >>= 1) {
        if (t < s) { r1[t] += r1[t + s]; r2[t] += r2[t + s]; }
        __syncthreads();
    }
    if (t == 0) { asrc[row] = r1[0]; adst[row] = r2[0]; }
}

// ---------------- segment max of leaky_relu(asrc[s]+adst[d]) over dst --------
__global__ void edge_max(const int* __restrict__ ei, const float* __restrict__ asrc,
                         const float* __restrict__ adst, unsigned* __restrict__ emax,
                         int nE, int nN)
{
    int e = blockIdx.x * blockDim.x + threadIdx.x;
    if (e >= nE + nN) return;
    int s, d;
    if (e < nE) { s = ei[e]; d = ei[nE + e]; }
    else        { s = d = e - nE; }
    float ev = leaky02(asrc[s] + adst[d]);
    atomicMax(&emax[d], fenc(ev));
}

// ---------------- agg[d] += e_exp * h[s] ; den[d] += e_exp -------------------
// 128-thread group per edge (2 groups / block)
__global__ void edge_agg(const int* __restrict__ ei, const float* __restrict__ asrc,
                         const float* __restrict__ adst, const unsigned* __restrict__ emax,
                         const float* __restrict__ h, float* __restrict__ agg,
                         float* __restrict__ den, int nE, int nN)
{
    const int g = threadIdx.x >> 7;
    const int c = threadIdx.x & 127;
    int e = blockIdx.x * 2 + g;
    if (e >= nE + nN) return;
    int s, d;
    if (e < nE) { s = ei[e]; d = ei[nE + e]; }
    else        { s = d = e - nE; }
    float ev = leaky02(asrc[s] + adst[d]);
    float ex = expf(ev - fdec(emax[d]));
    if (c == 0) atomicAdd(&den[d], ex);
    atomicAdd(&agg[(size_t)d * 128 + c], ex * h[(size_t)s * 128 + c]);
}

// ---------------- x = relu(agg/den + bias), IN PLACE -------------------------
__global__ void finalize(float* __restrict__ agg, const float* __restrict__ den,
                         const float* __restrict__ bias, int nN)
{
    int i = blockIdx.x * blockDim.x + threadIdx.x;
    if (i >= nN * 128) return;
    int c = i & 127, n = i >> 7;
    float v = agg[i] / den[n] + bias[c];
    agg[i] = fmaxf(v, 0.f);
}

// ---------------- column sum of x [nN,128] -----------------------------------
__global__ void col_sum(const float* __restrict__ x, float* __restrict__ sum, int nN)
{
    const int t = threadIdx.x;  // 128
    float acc = 0.f;
    for (int i = blockIdx.x; i < nN; i += gridDim.x)
        acc += x[(size_t)i * 128 + t];
    atomicAdd(&sum[t], acc);
}

// ---------------- sum over edges of relu(ef @ We + be) -----------------------
// 128 threads (2 waves); each wave holds the 64-wide ef row in lanes, shuffles.
__global__ void edge_emb_mean(const float* __restrict__ ef, const float* __restrict__ We,
                              const float* __restrict__ be, float* __restrict__ sume, int nE)
{
    const int t = threadIdx.x;       // 0..127 (output channel)
    const int lane = t & 63;
    const float bias = be[t];
    float wcol[64];
#pragma unroll
    for (int k = 0; k < 64; ++k) wcol[k] = We[k * 128 + t];

    float acc = 0.f;
    for (int e = blockIdx.x; e < nE; e += gridDim.x) {
        float myef = ef[(size_t)e * 64 + lane];
        float dsum = bias;
#pragma unroll
        for (int k = 0; k < 64; ++k)
            dsum += __shfl(myef, k, 64) * wcol[k];
        acc += fmaxf(dsum, 0.f);
    }
    atomicAdd(&sume[t], acc);
}

// out offsets: node_feats 0, edge_logits 6400, num_nodes 8900, cell 8950, mu 8956, lv 9020
#define OFF_EDGE 6400
#define OFF_NN   8900
#define OFF_CELL 8950
#define OFF_MU   8956
#define OFF_LV   9020

// ---------------- VAE head part 1 (single block, 128 threads) ----------------
__global__ void head1(const float* __restrict__ sumx, const float* __restrict__ sume,
                      const float* __restrict__ eps,
                      const float* __restrict__ Wc,   const float* __restrict__ bc,
                      const float* __restrict__ Wmu,  const float* __restrict__ bmu,
                      const float* __restrict__ Wlv,  const float* __restrict__ blv,
                      const float* __restrict__ Wl2h, const float* __restrict__ bl2h,
                      const float* __restrict__ Wnh,  const float* __restrict__ bnh,
                      const float* __restrict__ Weh,  const float* __restrict__ beh,
                      const float* __restrict__ Wnn,  const float* __restrict__ bnn,
                      const float* __restrict__ Wcp,  const float* __restrict__ bcp,
                      float* __restrict__ hscr, float* __restrict__ out, int nN, int nE)
{
    const int t = threadIdx.x;  // 128
    __shared__ float ge[256];
    __shared__ float g[128];
    __shared__ float z[64];
    __shared__ float h[128];

    ge[t]       = sumx[t] * (1.0f / (float)nN);
    ge[128 + t] = sume[t] * (1.0f / (float)nE);
    __syncthreads();

    {   // g = relu(graph_emb @ Wc + bc)
        float acc = bc[t];
        for (int i = 0; i < 256; ++i) acc += ge[i] * Wc[i * 128 + t];
        g[t] = fmaxf(acc, 0.f);
    }
    __syncthreads();

    if (t < 64) {  // mu, log_var, z
        float m = bmu[t], lv = blv[t];
        for (int i = 0; i < 128; ++i) {
            float gi = g[i];
            m  += gi * Wmu[i * 64 + t];
            lv += gi * Wlv[i * 64 + t];
        }
        out[OFF_MU + t] = m;
        out[OFF_LV + t] = lv;
        z[t] = m + eps[t] * expf(0.5f * lv);
    }
    __syncthreads();

    {   // h = relu(z @ Wl2h + bl2h)
        float acc = bl2h[t];
        for (int i = 0; i < 64; ++i) acc += z[i] * Wl2h[i * 128 + t];
        h[t] = fmaxf(acc, 0.f);
    }
    __syncthreads();

    {   // node_h, edge_h
        float nh = bnh[t], eh = beh[t];
        for (int i = 0; i < 128; ++i) {
            float hi = h[i];
            nh += hi * Wnh[i * 128 + t];
            eh += hi * Weh[i * 128 + t];
        }
        hscr[t]       = fmaxf(nh, 0.f);
        hscr[128 + t] = fmaxf(eh, 0.f);
    }

    if (t < 50) {
        float a = bnn[t];
        for (int i = 0; i < 128; ++i) a += h[i] * Wnn[i * 50 + t];
        out[OFF_NN + t] = a;
    }
    if (t < 6) {
        float a = bcp[t];
        for (int i = 0; i < 128; ++i) a += h[i] * Wcp[i * 6 + t];
        out[OFF_CELL + t] = a;
    }
}

// ---------------- VAE head part 2: node_feats + edge_logits ------------------
__global__ void head2(const float* __restrict__ hscr,
                      const float* __restrict__ Wnf, const float* __restrict__ bnf,
                      const float* __restrict__ Wee, const float* __restrict__ bee,
                      float* __restrict__ out)
{
    __shared__ float nh[128];
    __shared__ float eh[128];
    const int t = threadIdx.x;  // 256
    if (t < 128) nh[t] = hscr[t];
    else         eh[t - 128] = hscr[t];
    __syncthreads();

    int j = blockIdx.x * 256 + t;
    if (j < 6400) {
        float a = bnf[j];
#pragma unroll 16
        for (int i = 0; i < 128; ++i) a += nh[i] * Wnf[i * 6400 + j];
        out[j] = a;
    } else if (j < 8900) {
        int jj = j - 6400;
        float a = bee[jj];
#pragma unroll 16
        for (int i = 0; i < 128; ++i) a += eh[i] * Wee[i * 2500 + jj];
        out[OFF_EDGE + jj] = a;
    }
}

extern "C" void kernel_launch(void* const* d_in, const int* in_sizes, int n_in,
                              void* d_out, int out_size, void* d_ws, size_t ws_size,
                              hipStream_t stream)
{
    const float* x0  = (const float*)d_in[0];
    const int*   ei  = (const int*)d_in[1];
    const float* ef  = (const float*)d_in[2];
    const float* eps = (const float*)d_in[3];
    const float *W1 = (const float*)d_in[4],  *as1 = (const float*)d_in[5],
                *ad1 = (const float*)d_in[6], *b1 = (const float*)d_in[7];
    const float *W2 = (const float*)d_in[8],  *as2 = (const float*)d_in[9],
                *ad2 = (const float*)d_in[10], *b2 = (const float*)d_in[11];
    const float *We = (const float*)d_in[12], *be = (const float*)d_in[13];
    const float *Wc = (const float*)d_in[14], *bc = (const float*)d_in[15];
    const float *Wmu = (const float*)d_in[16], *bmu = (const float*)d_in[17];
    const float *Wlv = (const float*)d_in[18], *blv = (const float*)d_in[19];
    const float *Wl2h = (const float*)d_in[20], *bl2h = (const float*)d_in[21];
    const float *Wnh = (const float*)d_in[22], *bnh = (const float*)d_in[23];
    const float *Wnf = (const float*)d_in[24], *bnf = (const float*)d_in[25];
    const float *Weh = (const float*)d_in[26], *beh = (const float*)d_in[27];
    const float *Wee = (const float*)d_in[28], *bee = (const float*)d_in[29];
    const float *Wnn = (const float*)d_in[30], *bnn = (const float*)d_in[31];
    const float *Wcp = (const float*)d_in[32], *bcp = (const float*)d_in[33];
    float* out = (float*)d_out;

    const int nN = in_sizes[0] / 128;
    const int nE = in_sizes[1] / 2;
    const int total = nE + nN;
    const size_t NF = (size_t)nN * 128;

    // workspace layout (floats): A[NF] | B[NF] | EMAX[nN] | DEN[nN] | ASRC[nN]
    //                            | ADST[nN] | SUMX[128] | SUME[128] | HSCR[256]
    float* ws = (float*)d_ws;
    float*    A    = ws;
    float*    B    = A + NF;
    unsigned* EMAX = (unsigned*)(B + NF);
    float*    DEN  = (float*)(EMAX + nN);
    float*    ASRC = DEN + nN;
    float*    ADST = ASRC + nN;
    float*    SUMX = ADST + nN;    // 128
    float*    SUME = SUMX + 128;   // 128
    float*    HSCR = SUME + 128;   // 256

    const int nzero1 = (int)(NF + 4 * (size_t)nN + 512);  // B..HSCR end
    const int nzero2 = (int)(NF + 2 * (size_t)nN);        // B, EMAX, DEN

    // ---------- GAT layer 1 ----------
    zero_f32<<<2048, 256, 0, stream>>>(B, nzero1);
    gemm_alpha<<<nN, 128, 0, stream>>>(x0, W1, as1, ad1, A, ASRC, ADST);
    edge_max<<<(total + 255) / 256, 256, 0, stream>>>(ei, ASRC, ADST, EMAX, nE, nN);
    edge_agg<<<(total + 1) / 2, 256, 0, stream>>>(ei, ASRC, ADST, EMAX, A, B, DEN, nE, nN);
    finalize<<<(nN * 128 + 255) / 256, 256, 0, stream>>>(B, DEN, b1, nN);   // X1 in B

    // ---------- GAT layer 2 ----------
    gemm_alpha<<<nN, 128, 0, stream>>>(B, W2, as2, ad2, A, ASRC, ADST);     // h2 in A
    zero_f32<<<2048, 256, 0, stream>>>(B, nzero2);                          // B, EMAX, DEN
    edge_max<<<(total + 255) / 256, 256, 0, stream>>>(ei, ASRC, ADST, EMAX, nE, nN);
    edge_agg<<<(total + 1) / 2, 256, 0, stream>>>(ei, ASRC, ADST, EMAX, A, B, DEN, nE, nN);
    finalize<<<(nN * 128 + 255) / 256, 256, 0, stream>>>(B, DEN, b2, nN);   // X2 in B

    // ---------- means ----------
    col_sum<<<256, 128, 0, stream>>>(B, SUMX, nN);
    edge_emb_mean<<<512, 128, 0, stream>>>(ef, We, be, SUME, nE);

    // ---------- head ----------
    head1<<<1, 128, 0, stream>>>(SUMX, SUME, eps, Wc, bc, Wmu, bmu, Wlv, blv,
                                 Wl2h, bl2h, Wnh, bnh, Weh, beh, Wnn, bnn, Wcp, bcp,
                                 HSCR, out, nN, nE);
    head2<<<(8900 + 255) / 256, 256, 0, stream>>>(HSCR, Wnf, bnf, Wee, bee, out);
}

// Round 4
// 1646.483 us; speedup vs baseline: 3.0378x; 3.0378x over previous
//
#include <hip/hip_runtime.h>
#include <cstddef>

// order-preserving float -> uint encoding for atomicMax over signed floats
__device__ __forceinline__ unsigned fenc(float f) {
    unsigned b = __float_as_uint(f);
    return (b & 0x80000000u) ? ~b : (b | 0x80000000u);
}
__device__ __forceinline__ float fdec(unsigned u) {
    return (u & 0x80000000u) ? __uint_as_float(u & 0x7fffffffu) : __uint_as_float(~u);
}

__device__ __forceinline__ float leaky02(float v) { return v > 0.f ? v : 0.2f * v; }

// ---------------- grid-stride zero fill --------------------------------------
__global__ void zero_f32(float* __restrict__ p, int n)
{
    for (int i = blockIdx.x * blockDim.x + threadIdx.x; i < n;
         i += gridDim.x * blockDim.x)
        p[i] = 0.f;
}

// ============================================================================
// gemm_alpha: h = x @ W (128x128), asrc = h.avs, adst = h.avd
// Tile: 128 rows x 128 cols per block, 256 threads, 8x8 micro-tile/thread.
// K=128 staged in two 64-chunks: xls [k][r] (transposed), wls [k][c].
// ============================================================================
__global__ __launch_bounds__(256) void gemm_alpha(
    const float* __restrict__ x, const float* __restrict__ W,
    const float* __restrict__ avs, const float* __restrict__ avd,
    float* __restrict__ h, float* __restrict__ asrc, float* __restrict__ adst,
    int nN)
{
    __shared__ float xls[64][128];   // [k][row] 32 KB
    __shared__ float wls[64][128];   // [k][col] 32 KB

    const int t  = threadIdx.x;
    const int rg = t >> 4;           // 16 row-groups x 8 rows
    const int cg = t & 15;           // 16 col-groups x 8 cols (pairs stride 32)
    const int Rb = blockIdx.x * 128;

    float av_[8], ad_[8];
#pragma unroll
    for (int p = 0; p < 4; ++p) {
        int c = cg * 2 + 32 * p;
        av_[2*p]   = avs[c];   av_[2*p+1]   = avs[c+1];
        ad_[2*p]   = avd[c];   ad_[2*p+1]   = avd[c+1];
    }

    float acc[8][8];
#pragma unroll
    for (int j = 0; j < 8; ++j)
#pragma unroll
        for (int i = 0; i < 8; ++i) acc[j][i] = 0.f;

    const int r = t >> 1, q = t & 1;
    const bool rok = (Rb + r) < nN;

    for (int kc = 0; kc < 2; ++kc) {
        // stage W chunk (flat copy of 8192 floats)
#pragma unroll
        for (int m = 0; m < 8; ++m) {
            int flat = t * 4 + m * 1024;
            *(float4*)&((float*)wls)[flat] = *(const float4*)&W[kc * 8192 + flat];
        }
        // stage x chunk transposed: xls[k][r]
#pragma unroll
        for (int m = 0; m < 8; ++m) {
            int f = q + 2 * m;       // float4 index 0..15 within 64-float k-chunk
            float4 v = rok ? *(const float4*)&x[(size_t)(Rb + r) * 128 + kc * 64 + f * 4]
                           : make_float4(0.f, 0.f, 0.f, 0.f);
            xls[f*4+0][r] = v.x; xls[f*4+1][r] = v.y;
            xls[f*4+2][r] = v.z; xls[f*4+3][r] = v.w;
        }
        __syncthreads();

        for (int k = 0; k < 64; ++k) {
            float4 a0 = *(float4*)&xls[k][rg * 8];
            float4 a1 = *(float4*)&xls[k][rg * 8 + 4];
            float av[8] = {a0.x, a0.y, a0.z, a0.w, a1.x, a1.y, a1.z, a1.w};
#pragma unroll
            for (int p = 0; p < 4; ++p) {
                float2 bv = *(float2*)&wls[k][cg * 2 + 32 * p];
#pragma unroll
                for (int j = 0; j < 8; ++j) {
                    acc[j][2*p]   += av[j] * bv.x;
                    acc[j][2*p+1] += av[j] * bv.y;
                }
            }
        }
        __syncthreads();
    }

    // write h (8 rows x 4 float2)
#pragma unroll
    for (int j = 0; j < 8; ++j) {
        int row = Rb + rg * 8 + j;
        if (row < nN) {
#pragma unroll
            for (int p = 0; p < 4; ++p) {
                float2 v; v.x = acc[j][2*p]; v.y = acc[j][2*p+1];
                *(float2*)&h[(size_t)row * 128 + cg * 2 + 32 * p] = v;
            }
        }
    }

    // alpha dot-products: reduce over 16 cg lanes (consecutive within wave)
    float s1[8], s2[8];
#pragma unroll
    for (int j = 0; j < 8; ++j) {
        float a1 = 0.f, a2 = 0.f;
#pragma unroll
        for (int i = 0; i < 8; ++i) { a1 += acc[j][i] * av_[i]; a2 += acc[j][i] * ad_[i]; }
        s1[j] = a1; s2[j] = a2;
    }
#pragma unroll
    for (int m = 1; m < 16; m <<= 1) {
#pragma unroll
        for (int j = 0; j < 8; ++j) {
            s1[j] += __shfl_xor(s1[j], m, 64);
            s2[j] += __shfl_xor(s2[j], m, 64);
        }
    }
    if (cg == 0) {
#pragma unroll
        for (int j = 0; j < 8; ++j) {
            int row = Rb + rg * 8 + j;
            if (row < nN) { asrc[row] = s1[j]; adst[row] = s2[j]; }
        }
    }
}

// ---------------- segment max of leaky_relu(asrc[s]+adst[d]) over dst --------
__global__ void edge_max(const int* __restrict__ ei, const float* __restrict__ asrc,
                         const float* __restrict__ adst, unsigned* __restrict__ emax,
                         int nE, int nN)
{
    int e = blockIdx.x * blockDim.x + threadIdx.x;
    if (e >= nE + nN) return;
    int s, d;
    if (e < nE) { s = ei[e]; d = ei[nE + e]; }
    else        { s = d = e - nE; }
    float ev = leaky02(asrc[s] + adst[d]);
    atomicMax(&emax[d], fenc(ev));
}

// ---------------- agg[d] += e_exp * h[s] ; den[d] += e_exp -------------------
__global__ void edge_agg(const int* __restrict__ ei, const float* __restrict__ asrc,
                         const float* __restrict__ adst, const unsigned* __restrict__ emax,
                         const float* __restrict__ h, float* __restrict__ agg,
                         float* __restrict__ den, int nE, int nN)
{
    const int g = threadIdx.x >> 7;
    const int c = threadIdx.x & 127;
    int e = blockIdx.x * 2 + g;
    if (e >= nE + nN) return;
    int s, d;
    if (e < nE) { s = ei[e]; d = ei[nE + e]; }
    else        { s = d = e - nE; }
    float ev = leaky02(asrc[s] + adst[d]);
    float ex = expf(ev - fdec(emax[d]));
    if (c == 0) atomicAdd(&den[d], ex);
    atomicAdd(&agg[(size_t)d * 128 + c], ex * h[(size_t)s * 128 + c]);
}

// ---------------- x = relu(agg/den + bias), IN PLACE -------------------------
__global__ void finalize(float* __restrict__ agg, const float* __restrict__ den,
                         const float* __restrict__ bias, int nN)
{
    int i = blockIdx.x * blockDim.x + threadIdx.x;
    if (i >= nN * 128) return;
    int c = i & 127, n = i >> 7;
    float v = agg[i] / den[n] + bias[c];
    agg[i] = fmaxf(v, 0.f);
}

// ---------------- column sum of x [nN,128] -----------------------------------
__global__ void col_sum(const float* __restrict__ x, float* __restrict__ sum, int nN)
{
    const int t = threadIdx.x;  // 128
    float acc = 0.f;
    for (int i = blockIdx.x; i < nN; i += gridDim.x)
        acc += x[(size_t)i * 128 + t];
    atomicAdd(&sum[t], acc);
}

// ============================================================================
// edge_emb_sum: sume[c] += sum over edges of relu(ef @ We + be)[c]
// Tile: 128 edges x 128 ch, 256 threads, 8x8 micro-tile, K=64 single chunk.
// efs staged transposed [k][e]; wls [k][c].
// ============================================================================
__global__ __launch_bounds__(256) void edge_emb_sum(
    const float* __restrict__ ef, const float* __restrict__ We,
    const float* __restrict__ be, float* __restrict__ sume, int nE)
{
    __shared__ float efs[64][128];   // [k][edge] 32 KB
    __shared__ float wls[64][128];   // [k][ch]   32 KB
    __shared__ float sacc[128];

    const int t  = threadIdx.x;
    const int eg = t >> 4;           // 16 edge-groups x 8 edges
    const int cg = t & 15;           // channel pairs at stride 32

    // stage We (flat 8192 floats)
#pragma unroll
    for (int m = 0; m < 8; ++m) {
        int flat = t * 4 + m * 1024;
        *(float4*)&((float*)wls)[flat] = *(const float4*)&We[flat];
    }
    if (t < 128) sacc[t] = 0.f;

    float bch[8];
#pragma unroll
    for (int p = 0; p < 4; ++p) {
        int c = cg * 2 + 32 * p;
        bch[2*p] = be[c]; bch[2*p+1] = be[c+1];
    }

    // stage ef tile transposed
    const int Eb = blockIdx.x * 128;
    const int e  = t >> 1, q = t & 1;
    const bool eok = (Eb + e) < nE;
    const size_t gbase = (size_t)(Eb + e) * 64;
#pragma unroll
    for (int m = 0; m < 8; ++m) {
        int f = q + 2 * m;           // float4 index 0..15
        float4 v = eok ? *(const float4*)&ef[gbase + f * 4]
                       : make_float4(0.f, 0.f, 0.f, 0.f);
        efs[f*4+0][e] = v.x; efs[f*4+1][e] = v.y;
        efs[f*4+2][e] = v.z; efs[f*4+3][e] = v.w;
    }
    __syncthreads();

    float acc[8][8];
#pragma unroll
    for (int j = 0; j < 8; ++j)
#pragma unroll
        for (int i = 0; i < 8; ++i) acc[j][i] = 0.f;

    for (int k = 0; k < 64; ++k) {
        float4 a0 = *(float4*)&efs[k][eg * 8];
        float4 a1 = *(float4*)&efs[k][eg * 8 + 4];
        float av[8] = {a0.x, a0.y, a0.z, a0.w, a1.x, a1.y, a1.z, a1.w};
#pragma unroll
        for (int p = 0; p < 4; ++p) {
            float2 bv = *(float2*)&wls[k][cg * 2 + 32 * p];
#pragma unroll
            for (int j = 0; j < 8; ++j) {
                acc[j][2*p]   += av[j] * bv.x;
                acc[j][2*p+1] += av[j] * bv.y;
            }
        }
    }

    // relu + reduce over this thread's 8 edges
    float rsum[8];
#pragma unroll
    for (int i = 0; i < 8; ++i) rsum[i] = 0.f;
#pragma unroll
    for (int j = 0; j < 8; ++j) {
        if (Eb + eg * 8 + j < nE) {
#pragma unroll
            for (int i = 0; i < 8; ++i)
                rsum[i] += fmaxf(acc[j][i] + bch[i], 0.f);
        }
    }

#pragma unroll
    for (int i = 0; i < 8; ++i) {
        int c = cg * 2 + 32 * (i >> 1) + (i & 1);
        atomicAdd(&sacc[c], rsum[i]);
    }
    __syncthreads();
    if (t < 128) atomicAdd(&sume[t], sacc[t]);
}

// out offsets: node_feats 0, edge_logits 6400, num_nodes 8900, cell 8950, mu 8956, lv 9020
#define OFF_EDGE 6400
#define OFF_NN   8900
#define OFF_CELL 8950
#define OFF_MU   8956
#define OFF_LV   9020

// ---------------- VAE head part 1 (single block, 128 threads) ----------------
__global__ void head1(const float* __restrict__ sumx, const float* __restrict__ sume,
                      const float* __restrict__ eps,
                      const float* __restrict__ Wc,   const float* __restrict__ bc,
                      const float* __restrict__ Wmu,  const float* __restrict__ bmu,
                      const float* __restrict__ Wlv,  const float* __restrict__ blv,
                      const float* __restrict__ Wl2h, const float* __restrict__ bl2h,
                      const float* __restrict__ Wnh,  const float* __restrict__ bnh,
                      const float* __restrict__ Weh,  const float* __restrict__ beh,
                      const float* __restrict__ Wnn,  const float* __restrict__ bnn,
                      const float* __restrict__ Wcp,  const float* __restrict__ bcp,
                      float* __restrict__ hscr, float* __restrict__ out, int nN, int nE)
{
    const int t = threadIdx.x;  // 128
    __shared__ float ge[256];
    __shared__ float g[128];
    __shared__ float z[64];
    __shared__ float h[128];

    ge[t]       = sumx[t] * (1.0f / (float)nN);
    ge[128 + t] = sume[t] * (1.0f / (float)nE);
    __syncthreads();

    {
        float acc = bc[t];
        for (int i = 0; i < 256; ++i) acc += ge[i] * Wc[i * 128 + t];
        g[t] = fmaxf(acc, 0.f);
    }
    __syncthreads();

    if (t < 64) {
        float m = bmu[t], lv = blv[t];
        for (int i = 0; i < 128; ++i) {
            float gi = g[i];
            m  += gi * Wmu[i * 64 + t];
            lv += gi * Wlv[i * 64 + t];
        }
        out[OFF_MU + t] = m;
        out[OFF_LV + t] = lv;
        z[t] = m + eps[t] * expf(0.5f * lv);
    }
    __syncthreads();

    {
        float acc = bl2h[t];
        for (int i = 0; i < 64; ++i) acc += z[i] * Wl2h[i * 128 + t];
        h[t] = fmaxf(acc, 0.f);
    }
    __syncthreads();

    {
        float nh = bnh[t], eh = beh[t];
        for (int i = 0; i < 128; ++i) {
            float hi = h[i];
            nh += hi * Wnh[i * 128 + t];
            eh += hi * Weh[i * 128 + t];
        }
        hscr[t]       = fmaxf(nh, 0.f);
        hscr[128 + t] = fmaxf(eh, 0.f);
    }

    if (t < 50) {
        float a = bnn[t];
        for (int i = 0; i < 128; ++i) a += h[i] * Wnn[i * 50 + t];
        out[OFF_NN + t] = a;
    }
    if (t < 6) {
        float a = bcp[t];
        for (int i = 0; i < 128; ++i) a += h[i] * Wcp[i * 6 + t];
        out[OFF_CELL + t] = a;
    }
}

// ---------------- VAE head part 2: node_feats + edge_logits ------------------
__global__ void head2(const float* __restrict__ hscr,
                      const float* __restrict__ Wnf, const float* __restrict__ bnf,
                      const float* __restrict__ Wee, const float* __restrict__ bee,
                      float* __restrict__ out)
{
    __shared__ float nh[128];
    __shared__ float eh[128];
    const int t = threadIdx.x;  // 256
    if (t < 128) nh[t] = hscr[t];
    else         eh[t - 128] = hscr[t];
    __syncthreads();

    int j = blockIdx.x * 256 + t;
    if (j < 6400) {
        float a = bnf[j];
#pragma unroll 16
        for (int i = 0; i < 128; ++i) a += nh[i] * Wnf[i * 6400 + j];
        out[j] = a;
    } else if (j < 8900) {
        int jj = j - 6400;
        float a = bee[jj];
#pragma unroll 16
        for (int i = 0; i < 128; ++i) a += eh[i] * Wee[i * 2500 + jj];
        out[OFF_EDGE + jj] = a;
    }
}

extern "C" void kernel_launch(void* const* d_in, const int* in_sizes, int n_in,
                              void* d_out, int out_size, void* d_ws, size_t ws_size,
                              hipStream_t stream)
{
    const float* x0  = (const float*)d_in[0];
    const int*   ei  = (const int*)d_in[1];
    const float* ef  = (const float*)d_in[2];
    const float* eps = (const float*)d_in[3];
    const float *W1 = (const float*)d_in[4],  *as1 = (const float*)d_in[5],
                *ad1 = (const float*)d_in[6], *b1 = (const float*)d_in[7];
    const float *W2 = (const float*)d_in[8],  *as2 = (const float*)d_in[9],
                *ad2 = (const float*)d_in[10], *b2 = (const float*)d_in[11];
    const float *We = (const float*)d_in[12], *be = (const float*)d_in[13];
    const float *Wc = (const float*)d_in[14], *bc = (const float*)d_in[15];
    const float *Wmu = (const float*)d_in[16], *bmu = (const float*)d_in[17];
    const float *Wlv = (const float*)d_in[18], *blv = (const float*)d_in[19];
    const float *Wl2h = (const float*)d_in[20], *bl2h = (const float*)d_in[21];
    const float *Wnh = (const float*)d_in[22], *bnh = (const float*)d_in[23];
    const float *Wnf = (const float*)d_in[24], *bnf = (const float*)d_in[25];
    const float *Weh = (const float*)d_in[26], *beh = (const float*)d_in[27];
    const float *Wee = (const float*)d_in[28], *bee = (const float*)d_in[29];
    const float *Wnn = (const float*)d_in[30], *bnn = (const float*)d_in[31];
    const float *Wcp = (const float*)d_in[32], *bcp = (const float*)d_in[33];
    float* out = (float*)d_out;

    const int nN = in_sizes[0] / 128;
    const int nE = in_sizes[1] / 2;
    const int total = nE + nN;
    const size_t NF = (size_t)nN * 128;

    // workspace layout (floats): A[NF] | B[NF] | EMAX[nN] | DEN[nN] | ASRC[nN]
    //                            | ADST[nN] | SUMX[128] | SUME[128] | HSCR[256]
    float* ws = (float*)d_ws;
    float*    A    = ws;
    float*    B    = A + NF;
    unsigned* EMAX = (unsigned*)(B + NF);
    float*    DEN  = (float*)(EMAX + nN);
    float*    ASRC = DEN + nN;
    float*    ADST = ASRC + nN;
    float*    SUMX = ADST + nN;    // 128
    float*    SUME = SUMX + 128;   // 128
    float*    HSCR = SUME + 128;   // 256

    const int nzero1 = (int)(NF + 4 * (size_t)nN + 512);  // B..HSCR end
    const int nzero2 = (int)(NF + 2 * (size_t)nN);        // B, EMAX, DEN

    const int nRowTiles  = (nN + 127) / 128;
    const int nEdgeTiles = (nE + 127) / 128;

    // ---------- GAT layer 1 ----------
    zero_f32<<<2048, 256, 0, stream>>>(B, nzero1);
    gemm_alpha<<<nRowTiles, 256, 0, stream>>>(x0, W1, as1, ad1, A, ASRC, ADST, nN);
    edge_max<<<(total + 255) / 256, 256, 0, stream>>>(ei, ASRC, ADST, EMAX, nE, nN);
    edge_agg<<<(total + 1) / 2, 256, 0, stream>>>(ei, ASRC, ADST, EMAX, A, B, DEN, nE, nN);
    finalize<<<(nN * 128 + 255) / 256, 256, 0, stream>>>(B, DEN, b1, nN);   // X1 in B

    // ---------- GAT layer 2 ----------
    gemm_alpha<<<nRowTiles, 256, 0, stream>>>(B, W2, as2, ad2, A, ASRC, ADST, nN);
    zero_f32<<<2048, 256, 0, stream>>>(B, nzero2);                          // B, EMAX, DEN
    edge_max<<<(total + 255) / 256, 256, 0, stream>>>(ei, ASRC, ADST, EMAX, nE, nN);
    edge_agg<<<(total + 1) / 2, 256, 0, stream>>>(ei, ASRC, ADST, EMAX, A, B, DEN, nE, nN);
    finalize<<<(nN * 128 + 255) / 256, 256, 0, stream>>>(B, DEN, b2, nN);   // X2 in B

    // ---------- means ----------
    col_sum<<<256, 128, 0, stream>>>(B, SUMX, nN);
    edge_emb_sum<<<nEdgeTiles, 256, 0, stream>>>(ef, We, be, SUME, nE);

    // ---------- head ----------
    head1<<<1, 128, 0, stream>>>(SUMX, SUME, eps, Wc, bc, Wmu, bmu, Wlv, blv,
                                 Wl2h, bl2h, Wnh, bnh, Weh, beh, Wnn, bnn, Wcp, bcp,
                                 HSCR, out, nN, nE);
    head2<<<(8900 + 255) / 256, 256, 0, stream>>>(HSCR, Wnf, bnf, Wee, bee, out);
}

// Round 5
// 1011.795 us; speedup vs baseline: 4.9434x; 1.6273x over previous
//
#include <hip/hip_runtime.h>
#include <cstddef>

__device__ __forceinline__ float leaky02(float v) { return v > 0.f ? v : 0.2f * v; }

// ---------------- grid-stride zero fill --------------------------------------
__global__ void zero_f32(float* __restrict__ p, int n)
{
    for (int i = blockIdx.x * blockDim.x + threadIdx.x; i < n;
         i += gridDim.x * blockDim.x)
        p[i] = 0.f;
}

// ================= CSR build (edge_index is constant -> build once/call) =====
__global__ void init_deg(int* __restrict__ off, int nN)
{
    int i = blockIdx.x * blockDim.x + threadIdx.x;
    if (i < nN) off[i] = 1;              // self-loop
}

__global__ void hist_deg(const int* __restrict__ ei, int* __restrict__ off, int nE)
{
    int e = blockIdx.x * blockDim.x + threadIdx.x;
    if (e < nE) atomicAdd(&off[ei[nE + e]], 1);
}

// single block, 1024 threads: in-place exclusive scan of off -> rs[0..nN]
__global__ __launch_bounds__(1024) void scan_deg(int* __restrict__ off,
                                                 int* __restrict__ rs, int nN)
{
    __shared__ int part[1024];
    const int t = threadIdx.x;
    const int chunk = (nN + 1023) / 1024;
    const int b = t * chunk;
    const int e = min(b + chunk, nN);
    int s = 0;
    for (int i = b; i < e; ++i) s += off[i];
    part[t] = s;
    __syncthreads();
    for (int d = 1; d < 1024; d <<= 1) {
        int v = (t >= d) ? part[t - d] : 0;
        __syncthreads();
        part[t] += v;
        __syncthreads();
    }
    int pre = part[t] - s;               // exclusive prefix
    for (int i = b; i < e; ++i) {
        int c = off[i];
        rs[i] = pre;
        off[i] = pre;                    // cursor for scatter
        pre += c;
    }
    if (t == 0) rs[nN] = part[1023];
}

__global__ void scatter_src(const int* __restrict__ ei, int* __restrict__ off,
                            int* __restrict__ csr, int nE, int nN)
{
    int e = blockIdx.x * blockDim.x + threadIdx.x;
    if (e >= nE + nN) return;
    int s, d;
    if (e < nE) { s = ei[e]; d = ei[nE + e]; }
    else        { s = d = e - nE; }
    int pos = atomicAdd(&off[d], 1);
    csr[pos] = s;
}

// ============================================================================
// gemm_alpha: h = x @ W (128x128), asrc = h.avs, adst = h.avd
// ============================================================================
__global__ __launch_bounds__(256) void gemm_alpha(
    const float* __restrict__ x, const float* __restrict__ W,
    const float* __restrict__ avs, const float* __restrict__ avd,
    float* __restrict__ h, float* __restrict__ asrc, float* __restrict__ adst,
    int nN)
{
    __shared__ float xls[64][128];   // [k][row]
    __shared__ float wls[64][128];   // [k][col]

    const int t  = threadIdx.x;
    const int rg = t >> 4;
    const int cg = t & 15;
    const int Rb = blockIdx.x * 128;

    float av_[8], ad_[8];
#pragma unroll
    for (int p = 0; p < 4; ++p) {
        int c = cg * 2 + 32 * p;
        av_[2*p] = avs[c]; av_[2*p+1] = avs[c+1];
        ad_[2*p] = avd[c]; ad_[2*p+1] = avd[c+1];
    }

    float acc[8][8];
#pragma unroll
    for (int j = 0; j < 8; ++j)
#pragma unroll
        for (int i = 0; i < 8; ++i) acc[j][i] = 0.f;

    const int r = t >> 1, q = t & 1;
    const bool rok = (Rb + r) < nN;

    for (int kc = 0; kc < 2; ++kc) {
#pragma unroll
        for (int m = 0; m < 8; ++m) {
            int flat = t * 4 + m * 1024;
            *(float4*)&((float*)wls)[flat] = *(const float4*)&W[kc * 8192 + flat];
        }
#pragma unroll
        for (int m = 0; m < 8; ++m) {
            int f = q + 2 * m;
            float4 v = rok ? *(const float4*)&x[(size_t)(Rb + r) * 128 + kc * 64 + f * 4]
                           : make_float4(0.f, 0.f, 0.f, 0.f);
            xls[f*4+0][r] = v.x; xls[f*4+1][r] = v.y;
            xls[f*4+2][r] = v.z; xls[f*4+3][r] = v.w;
        }
        __syncthreads();

        for (int k = 0; k < 64; ++k) {
            float4 a0 = *(float4*)&xls[k][rg * 8];
            float4 a1 = *(float4*)&xls[k][rg * 8 + 4];
            float av[8] = {a0.x, a0.y, a0.z, a0.w, a1.x, a1.y, a1.z, a1.w};
#pragma unroll
            for (int p = 0; p < 4; ++p) {
                float2 bv = *(float2*)&wls[k][cg * 2 + 32 * p];
#pragma unroll
                for (int j = 0; j < 8; ++j) {
                    acc[j][2*p]   += av[j] * bv.x;
                    acc[j][2*p+1] += av[j] * bv.y;
                }
            }
        }
        __syncthreads();
    }

#pragma unroll
    for (int j = 0; j < 8; ++j) {
        int row = Rb + rg * 8 + j;
        if (row < nN) {
#pragma unroll
            for (int p = 0; p < 4; ++p) {
                float2 v; v.x = acc[j][2*p]; v.y = acc[j][2*p+1];
                *(float2*)&h[(size_t)row * 128 + cg * 2 + 32 * p] = v;
            }
        }
    }

    float s1[8], s2[8];
#pragma unroll
    for (int j = 0; j < 8; ++j) {
        float a1 = 0.f, a2 = 0.f;
#pragma unroll
        for (int i = 0; i < 8; ++i) { a1 += acc[j][i] * av_[i]; a2 += acc[j][i] * ad_[i]; }
        s1[j] = a1; s2[j] = a2;
    }
#pragma unroll
    for (int m = 1; m < 16; m <<= 1) {
#pragma unroll
        for (int j = 0; j < 8; ++j) {
            s1[j] += __shfl_xor(s1[j], m, 64);
            s2[j] += __shfl_xor(s2[j], m, 64);
        }
    }
    if (cg == 0) {
#pragma unroll
        for (int j = 0; j < 8; ++j) {
            int row = Rb + rg * 8 + j;
            if (row < nN) { asrc[row] = s1[j]; adst[row] = s2[j]; }
        }
    }
}

// ============================================================================
// gat_aggregate: one wave per dst node. CSR gather, online softmax, fused
// divide+bias+relu. x[d,c] = relu( sum_e ex*h[s,c] / sum_e ex + bias[c] )
// ============================================================================
__global__ __launch_bounds__(256) void gat_aggregate(
    const int* __restrict__ rs, const int* __restrict__ csr,
    const float* __restrict__ asrc, const float* __restrict__ adst,
    const float* __restrict__ h, const float* __restrict__ bias,
    float* __restrict__ x, int nN)
{
    const int w    = blockIdx.x * 4 + (threadIdx.x >> 6);
    const int lane = threadIdx.x & 63;
    if (w >= nN) return;

    const int beg = rs[w], end = rs[w + 1];
    const float ad = adst[w];

    // phase A: segment max
    float mx = -3.402823466e+38f;
    for (int i = beg + lane; i < end; i += 64)
        mx = fmaxf(mx, leaky02(asrc[csr[i]] + ad));
#pragma unroll
    for (int m = 32; m > 0; m >>= 1)
        mx = fmaxf(mx, __shfl_xor(mx, m, 64));

    // phase B: accumulate
    float acc0 = 0.f, acc1 = 0.f, dsum = 0.f;
    for (int chunk = beg; chunk < end; chunk += 64) {
        int i = chunk + lane;
        bool ok = i < end;
        int s = ok ? csr[i] : 0;
        float ex = ok ? expf(leaky02(asrc[s] + ad) - mx) : 0.f;
        dsum += ex;
        int cnt = min(64, end - chunk);
        for (int j = 0; j < cnt; ++j) {
            int   sj  = __shfl(s, j, 64);
            float exj = __shfl(ex, j, 64);
            const float* hp = &h[(size_t)sj * 128];
            acc0 += exj * hp[lane];
            acc1 += exj * hp[64 + lane];
        }
    }
#pragma unroll
    for (int m = 32; m > 0; m >>= 1)
        dsum += __shfl_xor(dsum, m, 64);

    const float inv = 1.f / dsum;
    x[(size_t)w * 128 + lane]      = fmaxf(acc0 * inv + bias[lane], 0.f);
    x[(size_t)w * 128 + 64 + lane] = fmaxf(acc1 * inv + bias[64 + lane], 0.f);
}

// ---------------- column sum of x [nN,128] -----------------------------------
__global__ void col_sum(const float* __restrict__ x, float* __restrict__ sum, int nN)
{
    const int t = threadIdx.x;  // 128
    float acc = 0.f;
    for (int i = blockIdx.x; i < nN; i += gridDim.x)
        acc += x[(size_t)i * 128 + t];
    atomicAdd(&sum[t], acc);
}

// ============================================================================
// edge_emb_sum: sume[c] += sum over edges of relu(ef @ We + be)[c]
// ============================================================================
__global__ __launch_bounds__(256) void edge_emb_sum(
    const float* __restrict__ ef, const float* __restrict__ We,
    const float* __restrict__ be, float* __restrict__ sume, int nE)
{
    __shared__ float efs[64][128];
    __shared__ float wls[64][128];
    __shared__ float sacc[128];

    const int t  = threadIdx.x;
    const int eg = t >> 4;
    const int cg = t & 15;

#pragma unroll
    for (int m = 0; m < 8; ++m) {
        int flat = t * 4 + m * 1024;
        *(float4*)&((float*)wls)[flat] = *(const float4*)&We[flat];
    }
    if (t < 128) sacc[t] = 0.f;

    float bch[8];
#pragma unroll
    for (int p = 0; p < 4; ++p) {
        int c = cg * 2 + 32 * p;
        bch[2*p] = be[c]; bch[2*p+1] = be[c+1];
    }

    const int Eb = blockIdx.x * 128;
    const int e  = t >> 1, q = t & 1;
    const bool eok = (Eb + e) < nE;
    const size_t gbase = (size_t)(Eb + e) * 64;
#pragma unroll
    for (int m = 0; m < 8; ++m) {
        int f = q + 2 * m;
        float4 v = eok ? *(const float4*)&ef[gbase + f * 4]
                       : make_float4(0.f, 0.f, 0.f, 0.f);
        efs[f*4+0][e] = v.x; efs[f*4+1][e] = v.y;
        efs[f*4+2][e] = v.z; efs[f*4+3][e] = v.w;
    }
    __syncthreads();

    float acc[8][8];
#pragma unroll
    for (int j = 0; j < 8; ++j)
#pragma unroll
        for (int i = 0; i < 8; ++i) acc[j][i] = 0.f;

    for (int k = 0; k < 64; ++k) {
        float4 a0 = *(float4*)&efs[k][eg * 8];
        float4 a1 = *(float4*)&efs[k][eg * 8 + 4];
        float av[8] = {a0.x, a0.y, a0.z, a0.w, a1.x, a1.y, a1.z, a1.w};
#pragma unroll
        for (int p = 0; p < 4; ++p) {
            float2 bv = *(float2*)&wls[k][cg * 2 + 32 * p];
#pragma unroll
            for (int j = 0; j < 8; ++j) {
                acc[j][2*p]   += av[j] * bv.x;
                acc[j][2*p+1] += av[j] * bv.y;
            }
        }
    }

    float rsum[8];
#pragma unroll
    for (int i = 0; i < 8; ++i) rsum[i] = 0.f;
#pragma unroll
    for (int j = 0; j < 8; ++j) {
        if (Eb + eg * 8 + j < nE) {
#pragma unroll
            for (int i = 0; i < 8; ++i)
                rsum[i] += fmaxf(acc[j][i] + bch[i], 0.f);
        }
    }

#pragma unroll
    for (int i = 0; i < 8; ++i) {
        int c = cg * 2 + 32 * (i >> 1) + (i & 1);
        atomicAdd(&sacc[c], rsum[i]);
    }
    __syncthreads();
    if (t < 128) atomicAdd(&sume[t], sacc[t]);
}

// out offsets
#define OFF_EDGE 6400
#define OFF_NN   8900
#define OFF_CELL 8950
#define OFF_MU   8956
#define OFF_LV   9020

// ---------------- VAE head part 1 (single block, 128 threads) ----------------
__global__ void head1(const float* __restrict__ sumx, const float* __restrict__ sume,
                      const float* __restrict__ eps,
                      const float* __restrict__ Wc,   const float* __restrict__ bc,
                      const float* __restrict__ Wmu,  const float* __restrict__ bmu,
                      const float* __restrict__ Wlv,  const float* __restrict__ blv,
                      const float* __restrict__ Wl2h, const float* __restrict__ bl2h,
                      const float* __restrict__ Wnh,  const float* __restrict__ bnh,
                      const float* __restrict__ Weh,  const float* __restrict__ beh,
                      const float* __restrict__ Wnn,  const float* __restrict__ bnn,
                      const float* __restrict__ Wcp,  const float* __restrict__ bcp,
                      float* __restrict__ hscr, float* __restrict__ out, int nN, int nE)
{
    const int t = threadIdx.x;  // 128
    __shared__ float ge[256];
    __shared__ float g[128];
    __shared__ float z[64];
    __shared__ float h[128];

    ge[t]       = sumx[t] * (1.0f / (float)nN);
    ge[128 + t] = sume[t] * (1.0f / (float)nE);
    __syncthreads();

    {
        float acc = bc[t];
        for (int i = 0; i < 256; ++i) acc += ge[i] * Wc[i * 128 + t];
        g[t] = fmaxf(acc, 0.f);
    }
    __syncthreads();

    if (t < 64) {
        float m = bmu[t], lv = blv[t];
        for (int i = 0; i < 128; ++i) {
            float gi = g[i];
            m  += gi * Wmu[i * 64 + t];
            lv += gi * Wlv[i * 64 + t];
        }
        out[OFF_MU + t] = m;
        out[OFF_LV + t] = lv;
        z[t] = m + eps[t] * expf(0.5f * lv);
    }
    __syncthreads();

    {
        float acc = bl2h[t];
        for (int i = 0; i < 64; ++i) acc += z[i] * Wl2h[i * 128 + t];
        h[t] = fmaxf(acc, 0.f);
    }
    __syncthreads();

    {
        float nh = bnh[t], eh = beh[t];
        for (int i = 0; i < 128; ++i) {
            float hi = h[i];
            nh += hi * Wnh[i * 128 + t];
            eh += hi * Weh[i * 128 + t];
        }
        hscr[t]       = fmaxf(nh, 0.f);
        hscr[128 + t] = fmaxf(eh, 0.f);
    }

    if (t < 50) {
        float a = bnn[t];
        for (int i = 0; i < 128; ++i) a += h[i] * Wnn[i * 50 + t];
        out[OFF_NN + t] = a;
    }
    if (t < 6) {
        float a = bcp[t];
        for (int i = 0; i < 128; ++i) a += h[i] * Wcp[i * 6 + t];
        out[OFF_CELL + t] = a;
    }
}

// ---------------- VAE head part 2: node_feats + edge_logits ------------------
__global__ void head2(const float* __restrict__ hscr,
                      const float* __restrict__ Wnf, const float* __restrict__ bnf,
                      const float* __restrict__ Wee, const float* __restrict__ bee,
                      float* __restrict__ out)
{
    __shared__ float nh[128];
    __shared__ float eh[128];
    const int t = threadIdx.x;  // 256
    if (t < 128) nh[t] = hscr[t];
    else         eh[t - 128] = hscr[t];
    __syncthreads();

    int j = blockIdx.x * 256 + t;
    if (j < 6400) {
        float a = bnf[j];
#pragma unroll 16
        for (int i = 0; i < 128; ++i) a += nh[i] * Wnf[i * 6400 + j];
        out[j] = a;
    } else if (j < 8900) {
        int jj = j - 6400;
        float a = bee[jj];
#pragma unroll 16
        for (int i = 0; i < 128; ++i) a += eh[i] * Wee[i * 2500 + jj];
        out[OFF_EDGE + jj] = a;
    }
}

extern "C" void kernel_launch(void* const* d_in, const int* in_sizes, int n_in,
                              void* d_out, int out_size, void* d_ws, size_t ws_size,
                              hipStream_t stream)
{
    const float* x0  = (const float*)d_in[0];
    const int*   ei  = (const int*)d_in[1];
    const float* ef  = (const float*)d_in[2];
    const float* eps = (const float*)d_in[3];
    const float *W1 = (const float*)d_in[4],  *as1 = (const float*)d_in[5],
                *ad1 = (const float*)d_in[6], *b1 = (const float*)d_in[7];
    const float *W2 = (const float*)d_in[8],  *as2 = (const float*)d_in[9],
                *ad2 = (const float*)d_in[10], *b2 = (const float*)d_in[11];
    const float *We = (const float*)d_in[12], *be = (const float*)d_in[13];
    const float *Wc = (const float*)d_in[14], *bc = (const float*)d_in[15];
    const float *Wmu = (const float*)d_in[16], *bmu = (const float*)d_in[17];
    const float *Wlv = (const float*)d_in[18], *blv = (const float*)d_in[19];
    const float *Wl2h = (const float*)d_in[20], *bl2h = (const float*)d_in[21];
    const float *Wnh = (const float*)d_in[22], *bnh = (const float*)d_in[23];
    const float *Wnf = (const float*)d_in[24], *bnf = (const float*)d_in[25];
    const float *Weh = (const float*)d_in[26], *beh = (const float*)d_in[27];
    const float *Wee = (const float*)d_in[28], *bee = (const float*)d_in[29];
    const float *Wnn = (const float*)d_in[30], *bnn = (const float*)d_in[31];
    const float *Wcp = (const float*)d_in[32], *bcp = (const float*)d_in[33];
    float* out = (float*)d_out;

    const int nN = in_sizes[0] / 128;
    const int nE = in_sizes[1] / 2;
    const size_t NF = (size_t)nN * 128;

    // workspace: floats A[NF] B[NF] ASRC[nN] ADST[nN] SUMX[128] SUME[128] HSCR[256]
    //            ints   RS[nN+1] OFF[nN] CSR[nE+nN]
    float* ws = (float*)d_ws;
    float* A    = ws;
    float* B    = A + NF;
    float* ASRC = B + NF;
    float* ADST = ASRC + nN;
    float* SUMX = ADST + nN;     // 128
    float* SUME = SUMX + 128;    // 128
    float* HSCR = SUME + 128;    // 256
    int*   RS   = (int*)(HSCR + 256);
    int*   OFF  = RS + (nN + 1);
    int*   CSR  = OFF + nN;

    const int nRowTiles  = (nN + 127) / 128;
    const int nEdgeTiles = (nE + 127) / 128;

    // ---------- CSR build (once; reused by both layers) ----------
    init_deg<<<(nN + 255) / 256, 256, 0, stream>>>(OFF, nN);
    hist_deg<<<(nE + 255) / 256, 256, 0, stream>>>(ei, OFF, nE);
    scan_deg<<<1, 1024, 0, stream>>>(OFF, RS, nN);
    scatter_src<<<(nE + nN + 255) / 256, 256, 0, stream>>>(ei, OFF, CSR, nE, nN);

    // ---------- GAT layer 1 ----------
    gemm_alpha<<<nRowTiles, 256, 0, stream>>>(x0, W1, as1, ad1, A, ASRC, ADST, nN);
    gat_aggregate<<<(nN + 3) / 4, 256, 0, stream>>>(RS, CSR, ASRC, ADST, A, b1, B, nN);

    // ---------- GAT layer 2 ----------
    gemm_alpha<<<nRowTiles, 256, 0, stream>>>(B, W2, as2, ad2, A, ASRC, ADST, nN);
    gat_aggregate<<<(nN + 3) / 4, 256, 0, stream>>>(RS, CSR, ASRC, ADST, A, b2, B, nN);

    // ---------- means ----------
    zero_f32<<<1, 256, 0, stream>>>(SUMX, 256);   // SUMX + SUME
    col_sum<<<256, 128, 0, stream>>>(B, SUMX, nN);
    edge_emb_sum<<<nEdgeTiles, 256, 0, stream>>>(ef, We, be, SUME, nE);

    // ---------- head ----------
    head1<<<1, 128, 0, stream>>>(SUMX, SUME, eps, Wc, bc, Wmu, bmu, Wlv, blv,
                                 Wl2h, bl2h, Wnh, bnh, Weh, beh, Wnn, bnn, Wcp, bcp,
                                 HSCR, out, nN, nE);
    head2<<<(8900 + 255) / 256, 256, 0, stream>>>(HSCR, Wnf, bnf, Wee, bee, out);
}

// Round 6
// 842.515 us; speedup vs baseline: 5.9367x; 1.2009x over previous
//
#include <hip/hip_runtime.h>
#include <hip/hip_bf16.h>
#include <cstddef>

typedef float f32x4 __attribute__((ext_vector_type(4)));
typedef short bf16x8 __attribute__((ext_vector_type(8)));

__device__ __forceinline__ float leaky02(float v) { return v > 0.f ? v : 0.2f * v; }

__device__ __forceinline__ short f2bs(float f) {
    union { __hip_bfloat16 h; short s; } u;
    u.h = __float2bfloat16(f);
    return u.s;
}

// ---------------- grid-stride zero fill --------------------------------------
__global__ void zero_f32(float* __restrict__ p, int n)
{
    for (int i = blockIdx.x * blockDim.x + threadIdx.x; i < n;
         i += gridDim.x * blockDim.x)
        p[i] = 0.f;
}

// ---------------- convert We to bf16 (once per call) -------------------------
__global__ void cvt_bf16(const float* __restrict__ src, short* __restrict__ dst, int n)
{
    int i = blockIdx.x * blockDim.x + threadIdx.x;
    if (i < n) dst[i] = f2bs(src[i]);
}

// ================= CSR build (edge_index constant -> build once/call) ========
__global__ void init_deg(int* __restrict__ off, int nN)
{
    int i = blockIdx.x * blockDim.x + threadIdx.x;
    if (i < nN) off[i] = 1;              // self-loop
}

__global__ void hist_deg(const int* __restrict__ ei, int* __restrict__ off, int nE)
{
    int e = blockIdx.x * blockDim.x + threadIdx.x;
    if (e < nE) atomicAdd(&off[ei[nE + e]], 1);
}

__global__ __launch_bounds__(1024) void scan_deg(int* __restrict__ off,
                                                 int* __restrict__ rs, int nN)
{
    __shared__ int part[1024];
    const int t = threadIdx.x;
    const int chunk = (nN + 1023) / 1024;
    const int b = t * chunk;
    const int e = min(b + chunk, nN);
    int s = 0;
    for (int i = b; i < e; ++i) s += off[i];
    part[t] = s;
    __syncthreads();
    for (int d = 1; d < 1024; d <<= 1) {
        int v = (t >= d) ? part[t - d] : 0;
        __syncthreads();
        part[t] += v;
        __syncthreads();
    }
    int pre = part[t] - s;
    for (int i = b; i < e; ++i) {
        int c = off[i];
        rs[i] = pre;
        off[i] = pre;
        pre += c;
    }
    if (t == 0) rs[nN] = part[1023];
}

__global__ void scatter_src(const int* __restrict__ ei, int* __restrict__ off,
                            int* __restrict__ csr, int nE, int nN)
{
    int e = blockIdx.x * blockDim.x + threadIdx.x;
    if (e >= nE + nN) return;
    int s, d;
    if (e < nE) { s = ei[e]; d = ei[nE + e]; }
    else        { s = d = e - nE; }
    int pos = atomicAdd(&off[d], 1);
    csr[pos] = s;
}

// ============================================================================
// gemm_alpha: h = x @ W (128x128), asrc = h.avs, adst = h.avd
// ============================================================================
__global__ __launch_bounds__(256) void gemm_alpha(
    const float* __restrict__ x, const float* __restrict__ W,
    const float* __restrict__ avs, const float* __restrict__ avd,
    float* __restrict__ h, float* __restrict__ asrc, float* __restrict__ adst,
    int nN)
{
    __shared__ float xls[64][128];
    __shared__ float wls[64][128];

    const int t  = threadIdx.x;
    const int rg = t >> 4;
    const int cg = t & 15;
    const int Rb = blockIdx.x * 128;

    float av_[8], ad_[8];
#pragma unroll
    for (int p = 0; p < 4; ++p) {
        int c = cg * 2 + 32 * p;
        av_[2*p] = avs[c]; av_[2*p+1] = avs[c+1];
        ad_[2*p] = avd[c]; ad_[2*p+1] = avd[c+1];
    }

    float acc[8][8];
#pragma unroll
    for (int j = 0; j < 8; ++j)
#pragma unroll
        for (int i = 0; i < 8; ++i) acc[j][i] = 0.f;

    const int r = t >> 1, q = t & 1;
    const bool rok = (Rb + r) < nN;

    for (int kc = 0; kc < 2; ++kc) {
#pragma unroll
        for (int m = 0; m < 8; ++m) {
            int flat = t * 4 + m * 1024;
            *(float4*)&((float*)wls)[flat] = *(const float4*)&W[kc * 8192 + flat];
        }
#pragma unroll
        for (int m = 0; m < 8; ++m) {
            int f = q + 2 * m;
            float4 v = rok ? *(const float4*)&x[(size_t)(Rb + r) * 128 + kc * 64 + f * 4]
                           : make_float4(0.f, 0.f, 0.f, 0.f);
            xls[f*4+0][r] = v.x; xls[f*4+1][r] = v.y;
            xls[f*4+2][r] = v.z; xls[f*4+3][r] = v.w;
        }
        __syncthreads();

        for (int k = 0; k < 64; ++k) {
            float4 a0 = *(float4*)&xls[k][rg * 8];
            float4 a1 = *(float4*)&xls[k][rg * 8 + 4];
            float av[8] = {a0.x, a0.y, a0.z, a0.w, a1.x, a1.y, a1.z, a1.w};
#pragma unroll
            for (int p = 0; p < 4; ++p) {
                float2 bv = *(float2*)&wls[k][cg * 2 + 32 * p];
#pragma unroll
                for (int j = 0; j < 8; ++j) {
                    acc[j][2*p]   += av[j] * bv.x;
                    acc[j][2*p+1] += av[j] * bv.y;
                }
            }
        }
        __syncthreads();
    }

#pragma unroll
    for (int j = 0; j < 8; ++j) {
        int row = Rb + rg * 8 + j;
        if (row < nN) {
#pragma unroll
            for (int p = 0; p < 4; ++p) {
                float2 v; v.x = acc[j][2*p]; v.y = acc[j][2*p+1];
                *(float2*)&h[(size_t)row * 128 + cg * 2 + 32 * p] = v;
            }
        }
    }

    float s1[8], s2[8];
#pragma unroll
    for (int j = 0; j < 8; ++j) {
        float a1 = 0.f, a2 = 0.f;
#pragma unroll
        for (int i = 0; i < 8; ++i) { a1 += acc[j][i] * av_[i]; a2 += acc[j][i] * ad_[i]; }
        s1[j] = a1; s2[j] = a2;
    }
#pragma unroll
    for (int m = 1; m < 16; m <<= 1) {
#pragma unroll
        for (int j = 0; j < 8; ++j) {
            s1[j] += __shfl_xor(s1[j], m, 64);
            s2[j] += __shfl_xor(s2[j], m, 64);
        }
    }
    if (cg == 0) {
#pragma unroll
        for (int j = 0; j < 8; ++j) {
            int row = Rb + rg * 8 + j;
            if (row < nN) { asrc[row] = s1[j]; adst[row] = s2[j]; }
        }
    }
}

// ============================================================================
// gat_aggregate: one wave per dst node. CSR gather, softmax, fused epilogue.
// (s, ex) staged in LDS per 64-edge chunk; j-loop uses broadcast LDS reads +
// one float2 vector load per edge, unrolled x4 for memory-level parallelism.
// ============================================================================
__global__ __launch_bounds__(256) void gat_aggregate(
    const int* __restrict__ rs, const int* __restrict__ csr,
    const float* __restrict__ asrc, const float* __restrict__ adst,
    const float* __restrict__ h, const float* __restrict__ bias,
    float* __restrict__ x, int nN)
{
    __shared__ int   sbuf[4][64];
    __shared__ float ebuf[4][64];

    const int widx = threadIdx.x >> 6;
    const int lane = threadIdx.x & 63;
    const int w    = blockIdx.x * 4 + widx;
    if (w >= nN) return;

    const int beg = rs[w], end = rs[w + 1];
    const float ad = adst[w];
    const float2* __restrict__ h2 = (const float2*)h;

    // phase A: segment max
    float mx = -3.402823466e+38f;
    for (int i = beg + lane; i < end; i += 64)
        mx = fmaxf(mx, leaky02(asrc[csr[i]] + ad));
#pragma unroll
    for (int m = 32; m > 0; m >>= 1)
        mx = fmaxf(mx, __shfl_xor(mx, m, 64));

    // phase B
    float2 acc = make_float2(0.f, 0.f);
    float dsum = 0.f;
    for (int chunk = beg; chunk < end; chunk += 64) {
        int i = chunk + lane;
        bool ok = i < end;
        int s = ok ? csr[i] : 0;
        float ex = ok ? expf(leaky02(asrc[s] + ad) - mx) : 0.f;
        dsum += ex;
        sbuf[widx][lane] = s;
        ebuf[widx][lane] = ex;

        const int cnt = min(64, end - chunk);
        int j = 0;
        for (; j + 4 <= cnt; j += 4) {
            int   s0 = sbuf[widx][j],   s1 = sbuf[widx][j+1];
            int   s2 = sbuf[widx][j+2], s3 = sbuf[widx][j+3];
            float e0 = ebuf[widx][j],   e1 = ebuf[widx][j+1];
            float e2 = ebuf[widx][j+2], e3 = ebuf[widx][j+3];
            float2 v0 = h2[(size_t)s0 * 64 + lane];
            float2 v1 = h2[(size_t)s1 * 64 + lane];
            float2 v2 = h2[(size_t)s2 * 64 + lane];
            float2 v3 = h2[(size_t)s3 * 64 + lane];
            acc.x += e0 * v0.x; acc.y += e0 * v0.y;
            acc.x += e1 * v1.x; acc.y += e1 * v1.y;
            acc.x += e2 * v2.x; acc.y += e2 * v2.y;
            acc.x += e3 * v3.x; acc.y += e3 * v3.y;
        }
        for (; j < cnt; ++j) {
            int   sj = sbuf[widx][j];
            float ej = ebuf[widx][j];
            float2 vj = h2[(size_t)sj * 64 + lane];
            acc.x += ej * vj.x; acc.y += ej * vj.y;
        }
    }
#pragma unroll
    for (int m = 32; m > 0; m >>= 1)
        dsum += __shfl_xor(dsum, m, 64);

    const float inv = 1.f / dsum;
    float2 bv = ((const float2*)bias)[lane];
    float2 o;
    o.x = fmaxf(acc.x * inv + bv.x, 0.f);
    o.y = fmaxf(acc.y * inv + bv.y, 0.f);
    ((float2*)x)[(size_t)w * 64 + lane] = o;
}

// ---------------- column sum of x [nN,128] -----------------------------------
__global__ void col_sum(const float* __restrict__ x, float* __restrict__ sum, int nN)
{
    const int t = threadIdx.x;  // 128
    float acc = 0.f;
    for (int i = blockIdx.x; i < nN; i += gridDim.x)
        acc += x[(size_t)i * 128 + t];
    atomicAdd(&sum[t], acc);
}

// ============================================================================
// edge_emb_mfma: sume[c] += sum over edges of relu(ef @ We + be)[c]
// MFMA 16x16x32 bf16; one wave per 16-edge tile (grid-stride over tiles).
// B-frags (We bf16) pinned in registers; A built from 4 coalesced float4
// loads + cvt. Epilogue: relu+bias in C layout (col=lane&15, row=grp*4+reg),
// accumulate per-wave col sums, reduce over grp, LDS block combine, atomics.
// ============================================================================
__global__ __launch_bounds__(256) void edge_emb_mfma(
    const float* __restrict__ ef, const short* __restrict__ Web,
    const float* __restrict__ be, float* __restrict__ sume, int nE)
{
    __shared__ float sacc[128];
    const int lane = threadIdx.x & 63;
    const int widx = threadIdx.x >> 6;
    const int gw   = blockIdx.x * 4 + widx;
    const int nW   = gridDim.x * 4;
    const int row  = lane & 15;     // A row (edge), B col (ch), C col
    const int grp  = lane >> 4;     // k-group / C row group

    if (threadIdx.x < 128) sacc[threadIdx.x] = 0.f;

    // B-frags: [col-tile p][k-chunk kc]; B[k][n]: k = kc*32 + grp*8 + j, n = p*16+row
    bf16x8 bf[8][2];
#pragma unroll
    for (int p = 0; p < 8; ++p)
#pragma unroll
        for (int kc = 0; kc < 2; ++kc) {
            bf16x8 v;
#pragma unroll
            for (int j = 0; j < 8; ++j)
                v[j] = Web[(kc * 32 + grp * 8 + j) * 128 + p * 16 + row];
            bf[p][kc] = v;
        }
    float bias[8];
#pragma unroll
    for (int p = 0; p < 8; ++p) bias[p] = be[p * 16 + row];

    float rsum[8];
#pragma unroll
    for (int p = 0; p < 8; ++p) rsum[p] = 0.f;

    const int nT = (nE + 15) >> 4;
    for (int t = gw; t < nT; t += nW) {
        const int Eb = t * 16;
        int e = Eb + row;
        if (e >= nE) e = 0;                       // clamp; rows masked in epilogue
        const float* ep = &ef[(size_t)e * 64 + grp * 8];
        float4 q0 = *(const float4*)ep;           // kc=0, j=0..3
        float4 q1 = *(const float4*)(ep + 4);     // kc=0, j=4..7
        float4 q2 = *(const float4*)(ep + 32);    // kc=1, j=0..3
        float4 q3 = *(const float4*)(ep + 36);    // kc=1, j=4..7
        bf16x8 a0, a1;
        a0[0]=f2bs(q0.x); a0[1]=f2bs(q0.y); a0[2]=f2bs(q0.z); a0[3]=f2bs(q0.w);
        a0[4]=f2bs(q1.x); a0[5]=f2bs(q1.y); a0[6]=f2bs(q1.z); a0[7]=f2bs(q1.w);
        a1[0]=f2bs(q2.x); a1[1]=f2bs(q2.y); a1[2]=f2bs(q2.z); a1[3]=f2bs(q2.w);
        a1[4]=f2bs(q3.x); a1[5]=f2bs(q3.y); a1[6]=f2bs(q3.z); a1[7]=f2bs(q3.w);

#pragma unroll
        for (int p = 0; p < 8; ++p) {
            f32x4 C = {0.f, 0.f, 0.f, 0.f};
            C = __builtin_amdgcn_mfma_f32_16x16x32_bf16(a0, bf[p][0], C, 0, 0, 0);
            C = __builtin_amdgcn_mfma_f32_16x16x32_bf16(a1, bf[p][1], C, 0, 0, 0);
#pragma unroll
            for (int r = 0; r < 4; ++r) {
                int edge = Eb + grp * 4 + r;
                if (edge < nE) rsum[p] += fmaxf(C[r] + bias[p], 0.f);
            }
        }
    }

    // reduce over the 4 grp groups (lanes sharing the same col)
#pragma unroll
    for (int p = 0; p < 8; ++p) {
        rsum[p] += __shfl_xor(rsum[p], 16, 64);
        rsum[p] += __shfl_xor(rsum[p], 32, 64);
    }
    __syncthreads();
    if (lane < 16) {
#pragma unroll
        for (int p = 0; p < 8; ++p)
            atomicAdd(&sacc[p * 16 + lane], rsum[p]);
    }
    __syncthreads();
    if (threadIdx.x < 128) atomicAdd(&sume[threadIdx.x], sacc[threadIdx.x]);
}

// out offsets
#define OFF_EDGE 6400
#define OFF_NN   8900
#define OFF_CELL 8950
#define OFF_MU   8956
#define OFF_LV   9020

// ---------------- VAE head part 1 (single block, 128 threads) ----------------
__global__ void head1(const float* __restrict__ sumx, const float* __restrict__ sume,
                      const float* __restrict__ eps,
                      const float* __restrict__ Wc,   const float* __restrict__ bc,
                      const float* __restrict__ Wmu,  const float* __restrict__ bmu,
                      const float* __restrict__ Wlv,  const float* __restrict__ blv,
                      const float* __restrict__ Wl2h, const float* __restrict__ bl2h,
                      const float* __restrict__ Wnh,  const float* __restrict__ bnh,
                      const float* __restrict__ Weh,  const float* __restrict__ beh,
                      const float* __restrict__ Wnn,  const float* __restrict__ bnn,
                      const float* __restrict__ Wcp,  const float* __restrict__ bcp,
                      float* __restrict__ hscr, float* __restrict__ out, int nN, int nE)
{
    const int t = threadIdx.x;  // 128
    __shared__ float ge[256];
    __shared__ float g[128];
    __shared__ float z[64];
    __shared__ float h[128];

    ge[t]       = sumx[t] * (1.0f / (float)nN);
    ge[128 + t] = sume[t] * (1.0f / (float)nE);
    __syncthreads();

    {
        float acc = bc[t];
        for (int i = 0; i < 256; ++i) acc += ge[i] * Wc[i * 128 + t];
        g[t] = fmaxf(acc, 0.f);
    }
    __syncthreads();

    if (t < 64) {
        float m = bmu[t], lv = blv[t];
        for (int i = 0; i < 128; ++i) {
            float gi = g[i];
            m  += gi * Wmu[i * 64 + t];
            lv += gi * Wlv[i * 64 + t];
        }
        out[OFF_MU + t] = m;
        out[OFF_LV + t] = lv;
        z[t] = m + eps[t] * expf(0.5f * lv);
    }
    __syncthreads();

    {
        float acc = bl2h[t];
        for (int i = 0; i < 64; ++i) acc += z[i] * Wl2h[i * 128 + t];
        h[t] = fmaxf(acc, 0.f);
    }
    __syncthreads();

    {
        float nh = bnh[t], eh = beh[t];
        for (int i = 0; i < 128; ++i) {
            float hi = h[i];
            nh += hi * Wnh[i * 128 + t];
            eh += hi * Weh[i * 128 + t];
        }
        hscr[t]       = fmaxf(nh, 0.f);
        hscr[128 + t] = fmaxf(eh, 0.f);
    }

    if (t < 50) {
        float a = bnn[t];
        for (int i = 0; i < 128; ++i) a += h[i] * Wnn[i * 50 + t];
        out[OFF_NN + t] = a;
    }
    if (t < 6) {
        float a = bcp[t];
        for (int i = 0; i < 128; ++i) a += h[i] * Wcp[i * 6 + t];
        out[OFF_CELL + t] = a;
    }
}

// ---------------- VAE head part 2: node_feats + edge_logits ------------------
__global__ void head2(const float* __restrict__ hscr,
                      const float* __restrict__ Wnf, const float* __restrict__ bnf,
                      const float* __restrict__ Wee, const float* __restrict__ bee,
                      float* __restrict__ out)
{
    __shared__ float nh[128];
    __shared__ float eh[128];
    const int t = threadIdx.x;  // 256
    if (t < 128) nh[t] = hscr[t];
    else         eh[t - 128] = hscr[t];
    __syncthreads();

    int j = blockIdx.x * 256 + t;
    if (j < 6400) {
        float a = bnf[j];
#pragma unroll 16
        for (int i = 0; i < 128; ++i) a += nh[i] * Wnf[i * 6400 + j];
        out[j] = a;
    } else if (j < 8900) {
        int jj = j - 6400;
        float a = bee[jj];
#pragma unroll 16
        for (int i = 0; i < 128; ++i) a += eh[i] * Wee[i * 2500 + jj];
        out[OFF_EDGE + jj] = a;
    }
}

extern "C" void kernel_launch(void* const* d_in, const int* in_sizes, int n_in,
                              void* d_out, int out_size, void* d_ws, size_t ws_size,
                              hipStream_t stream)
{
    const float* x0  = (const float*)d_in[0];
    const int*   ei  = (const int*)d_in[1];
    const float* ef  = (const float*)d_in[2];
    const float* eps = (const float*)d_in[3];
    const float *W1 = (const float*)d_in[4],  *as1 = (const float*)d_in[5],
                *ad1 = (const float*)d_in[6], *b1 = (const float*)d_in[7];
    const float *W2 = (const float*)d_in[8],  *as2 = (const float*)d_in[9],
                *ad2 = (const float*)d_in[10], *b2 = (const float*)d_in[11];
    const float *We = (const float*)d_in[12], *be = (const float*)d_in[13];
    const float *Wc = (const float*)d_in[14], *bc = (const float*)d_in[15];
    const float *Wmu = (const float*)d_in[16], *bmu = (const float*)d_in[17];
    const float *Wlv = (const float*)d_in[18], *blv = (const float*)d_in[19];
    const float *Wl2h = (const float*)d_in[20], *bl2h = (const float*)d_in[21];
    const float *Wnh = (const float*)d_in[22], *bnh = (const float*)d_in[23];
    const float *Wnf = (const float*)d_in[24], *bnf = (const float*)d_in[25];
    const float *Weh = (const float*)d_in[26], *beh = (const float*)d_in[27];
    const float *Wee = (const float*)d_in[28], *bee = (const float*)d_in[29];
    const float *Wnn = (const float*)d_in[30], *bnn = (const float*)d_in[31];
    const float *Wcp = (const float*)d_in[32], *bcp = (const float*)d_in[33];
    float* out = (float*)d_out;

    const int nN = in_sizes[0] / 128;
    const int nE = in_sizes[1] / 2;
    const size_t NF = (size_t)nN * 128;

    // workspace: floats A[NF] B[NF] ASRC[nN] ADST[nN] SUMX[128] SUME[128] HSCR[256]
    //            ints RS[nN+1] OFF[nN] CSR[nE+nN]; shorts WEB[8192]
    float* ws = (float*)d_ws;
    float* A    = ws;
    float* B    = A + NF;
    float* ASRC = B + NF;
    float* ADST = ASRC + nN;
    float* SUMX = ADST + nN;     // 128
    float* SUME = SUMX + 128;    // 128
    float* HSCR = SUME + 128;    // 256
    int*   RS   = (int*)(HSCR + 256);
    int*   OFF  = RS + (nN + 1);
    int*   CSR  = OFF + nN;
    short* WEB  = (short*)(CSR + (nE + nN));

    const int nRowTiles = (nN + 127) / 128;

    // ---------- CSR build + We bf16 conversion ----------
    init_deg<<<(nN + 255) / 256, 256, 0, stream>>>(OFF, nN);
    hist_deg<<<(nE + 255) / 256, 256, 0, stream>>>(ei, OFF, nE);
    scan_deg<<<1, 1024, 0, stream>>>(OFF, RS, nN);
    scatter_src<<<(nE + nN + 255) / 256, 256, 0, stream>>>(ei, OFF, CSR, nE, nN);
    cvt_bf16<<<32, 256, 0, stream>>>(We, WEB, 8192);

    // ---------- GAT layer 1 ----------
    gemm_alpha<<<nRowTiles, 256, 0, stream>>>(x0, W1, as1, ad1, A, ASRC, ADST, nN);
    gat_aggregate<<<(nN + 3) / 4, 256, 0, stream>>>(RS, CSR, ASRC, ADST, A, b1, B, nN);

    // ---------- GAT layer 2 ----------
    gemm_alpha<<<nRowTiles, 256, 0, stream>>>(B, W2, as2, ad2, A, ASRC, ADST, nN);
    gat_aggregate<<<(nN + 3) / 4, 256, 0, stream>>>(RS, CSR, ASRC, ADST, A, b2, B, nN);

    // ---------- means ----------
    zero_f32<<<1, 256, 0, stream>>>(SUMX, 256);   // SUMX + SUME
    col_sum<<<256, 128, 0, stream>>>(B, SUMX, nN);
    edge_emb_mfma<<<1024, 256, 0, stream>>>(ef, WEB, be, SUME, nE);

    // ---------- head ----------
    head1<<<1, 128, 0, stream>>>(SUMX, SUME, eps, Wc, bc, Wmu, bmu, Wlv, blv,
                                 Wl2h, bl2h, Wnh, bnh, Weh, beh, Wnn, bnn, Wcp, bcp,
                                 HSCR, out, nN, nE);
    head2<<<(8900 + 255) / 256, 256, 0, stream>>>(HSCR, Wnf, bnf, Wee, bee, out);
}